// Round 12
// baseline (297.020 us; speedup 1.0000x reference)
//
#include <hip/hip_runtime.h>

typedef unsigned int uint;
typedef unsigned short ushort;
typedef _Float16 h2 __attribute__((ext_vector_type(2)));
typedef _Float16 f16x8 __attribute__((ext_vector_type(8)));
typedef float f32x4 __attribute__((ext_vector_type(4)));

#define HW 65536
#define W_ 256
#define H_ 256
#define C_ 64

__device__ __forceinline__ ushort f2hu(float f) { union { ushort u; _Float16 h; } x; x.h = (_Float16)f; return x.u; }
__device__ __forceinline__ float hu2f(ushort u) { union { ushort u; _Float16 h; } x; x.u = u; return (float)x.h; }

#define MFMA16(a, b, c) __builtin_amdgcn_mfma_f32_16x16x32_f16((a), (b), (c), 0, 0, 0)

// ---------------- convert 6 weight matrices (4096 fp32 each) to f16, same [o][c] layout ----------------
__global__ __launch_bounds__(256) void wconv_k(const float* __restrict__ a0, const float* __restrict__ a1,
                                               const float* __restrict__ a2, const float* __restrict__ a3,
                                               const float* __restrict__ a4, const float* __restrict__ a5,
                                               ushort* __restrict__ dst) {
    int m = blockIdx.x;
    const float* src = m == 0 ? a0 : m == 1 ? a1 : m == 2 ? a2 : m == 3 ? a3 : m == 4 ? a4 : a5;
    ushort* d = dst + m * 4096;
    for (int i = threadIdx.x; i < 4096; i += 256) d[i] = f2hu(src[i]);
}

// ---------------- build Toeplitz B-fragments for the 7x7 pixel-attention conv ----------------
__global__ __launch_bounds__(256) void wpat_k(const float* __restrict__ pw, ushort* __restrict__ tbl) {
    int c = blockIdx.x;
    for (int i = threadIdx.x; i < 7168; i += 256) {
        int j = i & 7;
        int lane = (i >> 3) & 63;
        int f = i >> 9;              // 0..13
        int arr = f < 7 ? 0 : 1;
        int dy = f < 7 ? f : f - 7;
        int l15 = lane & 15, quad = lane >> 4;
        int k = quad * 8 + j;
        int t = k - l15 - 1;
        float v = (t >= 0 && t < 7) ? pw[c * 98 + arr * 49 + dy * 7 + t] : 0.0f;
        tbl[c * 7168 + i] = f2hu(v);
    }
}

// ---------------- fused dual conv1x1, 128-pixel tiles for 8 blocks/CU occupancy ----------------
// LDS [c][128pix] stride 132 halves (uint2-aligned staging; frag reads <=4-way; store reads 2-way).
__global__ __launch_bounds__(256, 4) void c1df_k(const float* __restrict__ xl,
                                                 const float* __restrict__ xr,
                                                 const ushort* __restrict__ wf16,
                                                 const float* __restrict__ bA0, const float* __restrict__ bB0,
                                                 const float* __restrict__ bA1, const float* __restrict__ bB1,
                                                 ushort* __restrict__ y0A, ushort* __restrict__ y0B,
                                                 ushort* __restrict__ y1A, ushort* __restrict__ y1B) {
    __shared__ ushort sS[64 * 132];     // staging [c][pix] then epilogue [o][pix], stride 132
    int side = blockIdx.y;
    const float* x = side ? xr : xl;
    const ushort* wfA = wf16 + side * 4096;
    const ushort* wfB = wf16 + (2 + side) * 4096;
    const float* biasA = side ? bA1 : bA0;
    const float* biasB = side ? bB1 : bB0;
    ushort* yAo = side ? y1A : y0A;
    ushort* yBo = side ? y1B : y0B;

    int tid = threadIdx.x;
    int wv = tid >> 6, lane = tid & 63;
    int l15 = lane & 15, quad = lane >> 4;
    int pix0 = blockIdx.x * 128;
    int b = pix0 >> 16, hw0 = pix0 & 65535;
    const float* xb = x + ((size_t)b << 22) + hw0;

    // ---- stage: 8 x float4 coalesced loads -> f16 LDS [c][pix] ----
#pragma unroll
    for (int i = 0; i < 8; ++i) {
        int idx = i * 256 + tid;        // 0..2047
        int cc = idx >> 5;              // channel 0..63
        int p4 = idx & 31;              // float4 index -> pixels p4*4..p4*4+3
        float4 v = *(const float4*)(xb + ((size_t)cc << 16) + p4 * 4);
        uint2 pk;
        pk.x = (uint)f2hu(v.x) | ((uint)f2hu(v.y) << 16);
        pk.y = (uint)f2hu(v.z) | ((uint)f2hu(v.w) << 16);
        *(uint2*)&sS[cc * 132 + p4 * 4] = pk;
    }
    __syncthreads();

    // ---- A-frags from LDS: pixel = wv*32+mt*16+l15, channel = kc*32+quad*8+j ----
    f16x8 aX[2][2];
#pragma unroll
    for (int mt = 0; mt < 2; ++mt) {
        int pixl = wv * 32 + mt * 16 + l15;
#pragma unroll
        for (int kc = 0; kc < 2; ++kc) {
            f16x8 a;
#pragma unroll
            for (int j = 0; j < 8; ++j) {
                int c = kc * 32 + quad * 8 + j;
                a[j] = *(const _Float16*)&sS[c * 132 + pixl];
            }
            aX[mt][kc] = a;
        }
    }

    for (int mat = 0; mat < 2; ++mat) {
        const ushort* wf = mat == 0 ? wfA : wfB;
        const float* bias = mat == 0 ? biasA : biasB;
        ushort* y = mat == 0 ? yAo : yBo;

        f16x8 bW[4][2];
#pragma unroll
        for (int nt = 0; nt < 4; ++nt)
#pragma unroll
            for (int kc = 0; kc < 2; ++kc)
                bW[nt][kc] = *(const f16x8*)(wf + (nt * 16 + l15) * 64 + kc * 32 + quad * 8);

        f32x4 acc[2][4];
#pragma unroll
        for (int mt = 0; mt < 2; ++mt)
#pragma unroll
            for (int nt = 0; nt < 4; ++nt) {
                f32x4 s = (f32x4)(0.0f);
                s = MFMA16(aX[mt][0], bW[nt][0], s);
                s = MFMA16(aX[mt][1], bW[nt][1], s);
                acc[mt][nt] = s;
            }

        __syncthreads();   // mat0: aX frag reads done; mat1: prev store reads done
#pragma unroll
        for (int nt = 0; nt < 4; ++nt) {
            int o = nt * 16 + l15;
            float bv = bias[o];
#pragma unroll
            for (int mt = 0; mt < 2; ++mt) {
                int pixl = wv * 32 + mt * 16 + quad * 4;
#pragma unroll
                for (int r = 0; r < 4; r += 2) {
                    h2 hh;
                    hh.x = (_Float16)(acc[mt][nt][r] + bv);
                    hh.y = (_Float16)(acc[mt][nt][r + 1] + bv);
                    *(h2*)&sS[o * 132 + pixl + r] = hh;
                }
            }
        }
        __syncthreads();
        // channels-last store: thread = (pixel 0..127, o-half); 4x uint4 coalesced
        int px = tid & 127, oh = tid >> 7;   // oh in {0,1} -> o 0..31 / 32..63
        ushort* yb = y + ((((size_t)b << 16) + hw0 + px) << 6) + oh * 32;
#pragma unroll
        for (int g = 0; g < 4; ++g) {
            ushort vs[8];
#pragma unroll
            for (int k = 0; k < 8; ++k) vs[k] = sS[(oh * 32 + g * 8 + k) * 132 + px];
            uint4 o;
            o.x = (uint)vs[0] | ((uint)vs[1] << 16);
            o.y = (uint)vs[2] | ((uint)vs[3] << 16);
            o.z = (uint)vs[4] | ((uint)vs[5] << 16);
            o.w = (uint)vs[6] | ((uint)vs[7] << 16);
            *(uint4*)(yb + g * 8) = o;
        }
    }
}

// ------- merged depthwise 3x3: Q path (mode 0, channels-last out) + V path (mode 1, plane out) -------
// grid (4 wtile, 64 hquad, 8 z = mode*4 + side*2 + b); one dispatch -> Q and V blocks co-schedule.
__global__ __launch_bounds__(256) void dwqv_k(const ushort* __restrict__ xA0, const ushort* __restrict__ xA1,
                                              const ushort* __restrict__ xB0, const ushort* __restrict__ xB1,
                                              const float* __restrict__ wq0, const float* __restrict__ wq1,
                                              const float* __restrict__ wv0, const float* __restrict__ wv1,
                                              const float* __restrict__ bq0, const float* __restrict__ bq1,
                                              const float* __restrict__ bv0, const float* __restrict__ bv1,
                                              ushort* __restrict__ oq0, ushort* __restrict__ oq1,
                                              ushort* __restrict__ ov0, ushort* __restrict__ ov1) {
    int z = blockIdx.z;
    int mode = z >> 2, side = (z >> 1) & 1, b = z & 1;
    const ushort* xcl = mode ? (side ? xB1 : xB0) : (side ? xA1 : xA0);
    const float* wgt  = mode ? (side ? wv1 : wv0) : (side ? wq1 : wq0);
    const float* bias = mode ? (side ? bv1 : bv0) : (side ? bq1 : bq0);
    ushort* out       = mode ? (side ? ov1 : ov0) : (side ? oq1 : oq0);

    __shared__ float sW[576];
    __shared__ ushort sT[4][64 * 66];
    int tid = threadIdx.x;
    for (int i = tid; i < 576; i += 256) sW[i] = wgt[i];
    __syncthreads();
    int c = tid & 63, wq = tid >> 6;
    int wt = blockIdx.x, h0 = blockIdx.y * 4;
    int wbase = wt * 64 + wq * 16;
    const float* wp = sW + c * 9;
    float bv = bias[c];
    float acc[4][16];
#pragma unroll
    for (int o = 0; o < 4; ++o)
#pragma unroll
        for (int i = 0; i < 16; ++i) acc[o][i] = bv;
    size_t plane = (size_t)b << 16;
#pragma unroll
    for (int r = 0; r < 6; ++r) {
        int hh = h0 - 1 + r;
        int hhc = hh < 0 ? 0 : (hh > 255 ? 255 : hh);
        bool okh = (hh >= 0 && hh <= 255);
        float v[18];
#pragma unroll
        for (int t = 0; t < 18; ++t) {
            int ww = wbase - 1 + t;
            int wwc = ww < 0 ? 0 : (ww > 255 ? 255 : ww);
            float xv = hu2f(xcl[((plane + (size_t)hhc * 256 + wwc) << 6) + c]);
            v[t] = (okh && ww >= 0 && ww <= 255) ? xv : 0.0f;
        }
#pragma unroll
        for (int o = 0; o < 4; ++o) {
            if (o >= r - 2 && o <= r) {          // weight row wr = r - o in 0..2
                int wr = r - o;
                float wa = wp[wr * 3], wb = wp[wr * 3 + 1], wc2 = wp[wr * 3 + 2];
#pragma unroll
                for (int i = 0; i < 16; ++i)
                    acc[o][i] += wa * v[i] + wb * v[i + 1] + wc2 * v[i + 2];
            }
        }
    }

    if (mode == 0) {
        // Q path: channels-last store, lane = c coalesced
#pragma unroll
        for (int o = 0; o < 4; ++o) {
            size_t obase = ((plane + (size_t)(h0 + o) * 256 + wbase) << 6) + c;
#pragma unroll
            for (int i = 0; i < 16; ++i)
                out[obase + ((size_t)i << 6)] = f2hu(acc[o][i]);
        }
    } else {
        // V path: transpose through LDS to plane layout [bh][c][w]
#pragma unroll
        for (int o = 0; o < 4; ++o)
#pragma unroll
            for (int i = 0; i < 16; i += 2) {
                h2 hh2;
                hh2.x = (_Float16)acc[o][i];
                hh2.y = (_Float16)acc[o][i + 1];
                *(h2*)&sT[o][c * 66 + wq * 16 + i] = hh2;
            }
        __syncthreads();
        int cr = tid >> 2, ch = tid & 3;
#pragma unroll
        for (int o = 0; o < 4; ++o) {
            uint vb[8];
#pragma unroll
            for (int k = 0; k < 8; ++k) vb[k] = *(const uint*)&sT[o][cr * 66 + ch * 16 + k * 2];
            uint4 q0, q1;
            q0.x = vb[0]; q0.y = vb[1]; q0.z = vb[2]; q0.w = vb[3];
            q1.x = vb[4]; q1.y = vb[5]; q1.z = vb[6]; q1.w = vb[7];
            size_t bh16 = ((size_t)b * 256 + h0 + o) * 16384;
            ushort* ob = out + bh16 + (size_t)cr * 256 + wt * 64 + ch * 16;
            *(uint4*)ob = q0;
            *(uint4*)(ob + 8) = q1;
        }
    }
}

// ---------------- combined MFMA attention (verified 256-thread version, 40us) ----------------
__global__ __launch_bounds__(256, 2) void att2_k(const ushort* __restrict__ Ql,
                                                 const ushort* __restrict__ Qr,
                                                 const ushort* __restrict__ Vl,
                                                 const ushort* __restrict__ Vr,
                                                 ushort* __restrict__ Fr2l,
                                                 ushort* __restrict__ Fl2r) {
    int bh = blockIdx.x;
    int tid = threadIdx.x;
    int wv = tid >> 6, lane = tid & 63;
    int l15 = lane & 15, quad = lane >> 4;
    __shared__ ushort sE[256 * 72];    // E row-major [p][kcol], stride 72
    __shared__ ushort sEt[64 * 264];   // E col-major [kcol][p], stride 264

    const ushort* qlb = Ql + (size_t)bh * 16384;
    const ushort* qrb = Qr + (size_t)bh * 16384;
    const ushort* vlb = Vl + (size_t)bh * 16384;
    const ushort* vrb = Vr + (size_t)bh * 16384;
    int p0 = wv * 64;
    int c0 = wv * 16;

    f16x8 aQ[4][2];
#pragma unroll
    for (int mt = 0; mt < 4; ++mt)
#pragma unroll
        for (int kc = 0; kc < 2; ++kc)
            aQ[mt][kc] = *(const f16x8*)(qlb + (p0 + mt * 16 + l15) * 64 + kc * 32 + quad * 8);

    f16x8 onesf;
#pragma unroll
    for (int i = 0; i < 8; ++i) onesf[i] = (_Float16)1.0f;

    f32x4 num1[4][4];
    f32x4 den[4];
#pragma unroll
    for (int mt = 0; mt < 4; ++mt) {
        den[mt] = (f32x4)(0.0f);
#pragma unroll
        for (int nt = 0; nt < 4; ++nt) num1[mt][nt] = (f32x4)(0.0f);
    }

    for (int kt = 0; kt < 4; ++kt) {
        int k0 = kt * 64;
        f32x4 S[4][4];
#pragma unroll
        for (int nt = 0; nt < 4; ++nt) {
            f16x8 bQ[2];
#pragma unroll
            for (int kc = 0; kc < 2; ++kc)
                bQ[kc] = *(const f16x8*)(qrb + (k0 + nt * 16 + l15) * 64 + kc * 32 + quad * 8);
#pragma unroll
            for (int mt = 0; mt < 4; ++mt) {
                f32x4 s = (f32x4)(0.0f);
                s = MFMA16(aQ[mt][0], bQ[0], s);
                s = MFMA16(aQ[mt][1], bQ[1], s);
                S[mt][nt] = s;
            }
        }
#pragma unroll
        for (int mt = 0; mt < 4; ++mt)
#pragma unroll
            for (int nt = 0; nt < 4; ++nt)
#pragma unroll
                for (int r = 0; r < 4; ++r)
                    S[mt][nt][r] = __expf(S[mt][nt][r] * 0.125f);

        __syncthreads();
#pragma unroll
        for (int mt = 0; mt < 4; ++mt)
#pragma unroll
            for (int nt = 0; nt < 4; ++nt)
#pragma unroll
                for (int r = 0; r < 4; ++r)
                    sE[(p0 + mt * 16 + quad * 4 + r) * 72 + nt * 16 + l15] = f2hu(S[mt][nt][r]);
#pragma unroll
        for (int mt = 0; mt < 4; ++mt)
#pragma unroll
            for (int nt = 0; nt < 4; ++nt)
#pragma unroll
            for (int pr = 0; pr < 4; pr += 2) {
                h2 hh;
                hh.x = (_Float16)S[mt][nt][pr];
                hh.y = (_Float16)S[mt][nt][pr + 1];
                *(h2*)&sEt[(nt * 16 + l15) * 264 + p0 + mt * 16 + quad * 4 + pr] = hh;
            }
        __syncthreads();

        f16x8 aE[4][2];
#pragma unroll
        for (int mt = 0; mt < 4; ++mt)
#pragma unroll
            for (int kc = 0; kc < 2; ++kc)
                aE[mt][kc] = *(const f16x8*)&sE[(p0 + mt * 16 + l15) * 72 + kc * 32 + quad * 8];
#pragma unroll
        for (int mt = 0; mt < 4; ++mt) {
            den[mt] = MFMA16(aE[mt][0], onesf, den[mt]);
            den[mt] = MFMA16(aE[mt][1], onesf, den[mt]);
        }
#pragma unroll
        for (int nt = 0; nt < 4; ++nt) {
            f16x8 bV[2];
#pragma unroll
            for (int kc = 0; kc < 2; ++kc)
                bV[kc] = *(const f16x8*)(vrb + (nt * 16 + l15) * 256 + k0 + kc * 32 + quad * 8);
#pragma unroll
            for (int mt = 0; mt < 4; ++mt) {
                num1[mt][nt] = MFMA16(aE[mt][0], bV[0], num1[mt][nt]);
                num1[mt][nt] = MFMA16(aE[mt][1], bV[1], num1[mt][nt]);
            }
        }
        f32x4 num2[4], den2[4];
#pragma unroll
        for (int mt = 0; mt < 4; ++mt) { num2[mt] = (f32x4)(0.0f); den2[mt] = (f32x4)(0.0f); }
        for (int pc = 0; pc < 8; ++pc) {
            f16x8 bL = *(const f16x8*)(vlb + (c0 + l15) * 256 + pc * 32 + quad * 8);
#pragma unroll
            for (int mt = 0; mt < 4; ++mt) {
                f16x8 aT = *(const f16x8*)&sEt[(mt * 16 + l15) * 264 + pc * 32 + quad * 8];
                num2[mt] = MFMA16(aT, bL, num2[mt]);
                den2[mt] = MFMA16(aT, onesf, den2[mt]);
            }
        }
#pragma unroll
        for (int mt = 0; mt < 4; ++mt)
#pragma unroll
            for (int r = 0; r < 4; ++r) {
                float v = num2[mt][r] * (1.0f / den2[mt][r]);
                Fl2r[(size_t)bh * 16384 + (k0 + mt * 16 + quad * 4 + r) * 64 + c0 + l15] = f2hu(v);
            }
    }
#pragma unroll
    for (int mt = 0; mt < 4; ++mt)
#pragma unroll
        for (int r = 0; r < 4; ++r) {
            float inv = 1.0f / den[mt][r];
#pragma unroll
            for (int nt = 0; nt < 4; ++nt) {
                float v = num1[mt][nt][r] * inv;
                Fr2l[(size_t)bh * 16384 + (p0 + mt * 16 + quad * 4 + r) * 64 + nt * 16 + l15] = f2hu(v);
            }
        }
}

// ------- pattn1 = lp3(F_r2l) + rp3(F_l2r) via MFMA; channels-last f16 in, NCHW f16 out -------
__global__ __launch_bounds__(256, 2) void p3m_k(const ushort* __restrict__ F1,
                                                const ushort* __restrict__ F2,
                                                const ushort* __restrict__ wf1,
                                                const float* __restrict__ b1,
                                                const ushort* __restrict__ wf2,
                                                const float* __restrict__ b2,
                                                ushort* __restrict__ outp) {
    __shared__ ushort sY[64 * 264];
    int tid = threadIdx.x;
    int wv = tid >> 6, lane = tid & 63;
    int l15 = lane & 15, quad = lane >> 4;
    int pix0 = blockIdx.x * 256;
    int b = pix0 >> 16, hw0 = pix0 & 65535;

    f32x4 acc[4][4];
#pragma unroll
    for (int mt = 0; mt < 4; ++mt)
#pragma unroll
        for (int nt = 0; nt < 4; ++nt) acc[mt][nt] = (f32x4)(0.0f);

    for (int mat = 0; mat < 2; ++mat) {
        const ushort* F = mat == 0 ? F1 : F2;
        const ushort* wf = mat == 0 ? wf1 : wf2;
        f16x8 aF[4][2], bW[4][2];
#pragma unroll
        for (int mt = 0; mt < 4; ++mt) {
            int pixg = pix0 + wv * 64 + mt * 16 + l15;
#pragma unroll
            for (int kc = 0; kc < 2; ++kc)
                aF[mt][kc] = *(const f16x8*)(F + (size_t)pixg * 64 + kc * 32 + quad * 8);
        }
#pragma unroll
        for (int nt = 0; nt < 4; ++nt)
#pragma unroll
            for (int kc = 0; kc < 2; ++kc)
                bW[nt][kc] = *(const f16x8*)(wf + (nt * 16 + l15) * 64 + kc * 32 + quad * 8);
#pragma unroll
        for (int mt = 0; mt < 4; ++mt)
#pragma unroll
            for (int nt = 0; nt < 4; ++nt) {
                acc[mt][nt] = MFMA16(aF[mt][0], bW[nt][0], acc[mt][nt]);
                acc[mt][nt] = MFMA16(aF[mt][1], bW[nt][1], acc[mt][nt]);
            }
    }

#pragma unroll
    for (int nt = 0; nt < 4; ++nt) {
        int o = nt * 16 + l15;
        float bv = b1[o] + b2[o];
#pragma unroll
        for (int mt = 0; mt < 4; ++mt) {
            int pixl = wv * 64 + mt * 16 + quad * 4;
#pragma unroll
            for (int r = 0; r < 4; r += 2) {
                h2 hh;
                hh.x = (_Float16)(acc[mt][nt][r] + bv);
                hh.y = (_Float16)(acc[mt][nt][r + 1] + bv);
                *(h2*)&sY[o * 264 + pixl + r] = hh;
            }
        }
    }
    __syncthreads();
    ushort* yb = outp + ((size_t)b << 22) + hw0;
#pragma unroll
    for (int i = 0; i < 16; ++i) {
        int o = wv * 16 + i;
        uint2 v = *(const uint2*)&sY[o * 264 + lane * 4];
        *(uint2*)(yb + ((size_t)o << 16) + lane * 4) = v;
    }
}

// ------- pixel attention 7x7 reflect + double sigmoid + blend, via Toeplitz MFMA -------
__global__ __launch_bounds__(256, 4) void p4m_k(const float* __restrict__ x_l,
                                                const float* __restrict__ x_r,
                                                const ushort* __restrict__ pt,
                                                const ushort* __restrict__ tbl,
                                                const float* __restrict__ pb,
                                                float* __restrict__ out) {
    __shared__ ushort s_t[22 * 320];
    __shared__ ushort p_t[22 * 320];
    int tid = threadIdx.x;
    int tile = blockIdx.x & 15;
    int bc = blockIdx.x >> 4;        // b*64 + c
    int c = bc & 63;
    int h0 = tile << 4;
    size_t cbase = (size_t)bc << 16;

    {
        int a = tid & 127, rr = tid >> 7;
        int k = 2 * a + 4;
        int slotbase = (k >> 3);
        for (int pass = 0; pass < 11; ++pass) {
            int row = pass * 2 + rr;
            int hh = h0 + row - 3;
            hh = hh < 0 ? -hh : (hh > 255 ? 510 - hh : hh);
            size_t rb = cbase + ((size_t)hh << 8);
            float2 xl2 = *(const float2*)(x_l + rb + 2 * a);
            float2 xr2 = *(const float2*)(x_r + rb + 2 * a);
            uint pv = *(const uint*)(pt + rb + 2 * a);
            h2 sh;
            sh.x = (_Float16)(xl2.x + xr2.x);
            sh.y = (_Float16)(xl2.y + xr2.y);
            int off = row * 320 + (((slotbase ^ (row & 7)) << 3) | (k & 7));
            *(h2*)&s_t[off] = sh;
            *(uint*)&p_t[off] = pv;
        }
    }
    if (tid < 176) {
        int row = tid >> 3, g = tid & 7;
        int k = g < 2 ? g * 2 : (g < 4 ? 260 + (g - 2) * 2 : 264 + (g - 4) * 2);
        h2 sh; uint pv;
        if (g < 4) {
            int hh = h0 + row - 3;
            hh = hh < 0 ? -hh : (hh > 255 ? 510 - hh : hh);
            size_t rb = cbase + ((size_t)hh << 8);
            int w0 = k - 4, w1 = k - 3;
            int s0 = w0 < 0 ? -w0 : (w0 > 255 ? 510 - w0 : w0);
            int s1 = w1 < 0 ? -w1 : (w1 > 255 ? 510 - w1 : w1);
            sh.x = (_Float16)(x_l[rb + s0] + x_r[rb + s0]);
            sh.y = (_Float16)(x_l[rb + s1] + x_r[rb + s1]);
            pv = (uint)pt[rb + s0] | ((uint)pt[rb + s1] << 16);
        } else {
            sh.x = (_Float16)0.0f; sh.y = (_Float16)0.0f;
            pv = 0;
        }
        int off = row * 320 + ((((k >> 3) ^ (row & 7)) << 3) | (k & 7));
        *(h2*)&s_t[off] = sh;
        *(uint*)&p_t[off] = pv;
    }

    int wv = tid >> 6, lane = tid & 63;
    int l15 = lane & 15, quad = lane >> 4;
    const ushort* tb = tbl + c * 7168;
    f16x8 bW[14];
#pragma unroll
    for (int f = 0; f < 14; ++f)
        bW[f] = *(const f16x8*)(tb + (f * 64 + lane) * 8);

    float bias = pb[c];
    f32x4 acc[4];
#pragma unroll
    for (int t = 0; t < 4; ++t) acc[t] = (f32x4)(bias);

    __syncthreads();

#pragma unroll
    for (int f = 0; f < 14; ++f) {
        int dy = f < 7 ? f : f - 7;
        const ushort* tp = f < 7 ? s_t : p_t;
        int row = l15 + dy;
        int rbase = row * 320;
        int rx = row & 7;
#pragma unroll
        for (int t = 0; t < 4; ++t) {
            int L = wv * 8 + 2 * t + quad;
            f16x8 aF = *(const f16x8*)&tp[rbase + ((L ^ rx) << 3)];
            acc[t] = MFMA16(aF, bW[f], acc[t]);
        }
    }

    int hrow = h0 + quad * 4;
#pragma unroll
    for (int t = 0; t < 4; ++t) {
        int w = wv * 64 + t * 16 + l15;
#pragma unroll
        for (int r = 0; r < 4; ++r) {
            size_t idx = cbase + (size_t)(hrow + r) * 256 + w;
            float z = acc[t][r];
            float s1 = 1.0f / (1.0f + __expf(-z));
            float a  = 1.0f / (1.0f + __expf(-s1));
            float xl = x_l[idx], xr = x_r[idx];
            out[idx] = xr + a * (xl - xr);
        }
    }
}

extern "C" void kernel_launch(void* const* d_in, const int* in_sizes, int n_in,
                              void* d_out, int out_size, void* d_ws, size_t ws_size,
                              hipStream_t stream) {
    const float* x_l = (const float*)d_in[0];
    const float* x_r = (const float*)d_in[1];
    const float* lp1_w1 = (const float*)d_in[2];
    const float* lp1_b1 = (const float*)d_in[3];
    const float* lp1_w2 = (const float*)d_in[4];
    const float* lp1_b2 = (const float*)d_in[5];
    const float* rp1_w1 = (const float*)d_in[6];
    const float* rp1_b1 = (const float*)d_in[7];
    const float* rp1_w2 = (const float*)d_in[8];
    const float* rp1_b2 = (const float*)d_in[9];
    const float* lp2_w1 = (const float*)d_in[10];
    const float* lp2_b1 = (const float*)d_in[11];
    const float* lp2_w2 = (const float*)d_in[12];
    const float* lp2_b2 = (const float*)d_in[13];
    const float* rp2_w1 = (const float*)d_in[14];
    const float* rp2_b1 = (const float*)d_in[15];
    const float* rp2_w2 = (const float*)d_in[16];
    const float* rp2_b2 = (const float*)d_in[17];
    const float* lp3_w = (const float*)d_in[18];
    const float* lp3_b = (const float*)d_in[19];
    const float* rp3_w = (const float*)d_in[20];
    const float* rp3_b = (const float*)d_in[21];
    const float* pa_w = (const float*)d_in[22];
    const float* pa_b = (const float*)d_in[23];

    const size_t N = (size_t)2 * 64 * 256 * 256;    // 8388608
    char* ws = (char*)d_ws;
    ushort* clA0 = (ushort*)ws;                     // N u16 (side0 Q-path c1 out / later pattn1 NCHW)
    ushort* wf16 = (ushort*)(ws + N * 2);           // 6 * 4096 f16 weights [o][c]
    ushort* tbl  = (ushort*)(ws + N * 2 + 6 * 4096 * 2);  // Toeplitz frags (~0.9MB)
    ushort* q_l   = (ushort*)(ws + N * 4);
    ushort* q_r   = q_l + N;
    ushort* v_l   = q_r + N;                        // plane layout
    ushort* v_r   = v_l + N;                        // plane layout
    ushort* f_r2l = v_r + N;
    ushort* f_l2r = f_r2l + N;
    ushort* clB0  = f_l2r + N;                      // side0 V-path c1 out
    ushort* clA1  = clB0 + N;                       // side1 Q-path
    ushort* clB1  = clA1 + N;                       // side1 V-path

    dim3 blk(256);
    dim3 g_c1(1024, 2);        // B*HW/128, side
    dim3 g_dw(4, 64, 8);       // wtile, hquad, mode*4+side*2+b
    dim3 g_att(512);           // b*h
    dim3 g_p3(512);            // B*HW/256
    dim3 g_p4(2048);           // (b*64+c)*16 + htile

    wconv_k<<<6, blk, 0, stream>>>(lp1_w1, rp1_w1, lp2_w1, rp2_w1, lp3_w, rp3_w, wf16);
    wpat_k<<<64, blk, 0, stream>>>(pa_w, tbl);

    c1df_k<<<g_c1, blk, 0, stream>>>(x_l, x_r, wf16,
                                     lp1_b1, lp2_b1, rp1_b1, rp2_b1,
                                     clA0, clB0, clA1, clB1);
    dwqv_k<<<g_dw, blk, 0, stream>>>(clA0, clA1, clB0, clB1,
                                     lp1_w2, rp1_w2, lp2_w2, rp2_w2,
                                     lp1_b2, rp1_b2, lp2_b2, rp2_b2,
                                     q_l, q_r, v_l, v_r);

    att2_k<<<g_att, blk, 0, stream>>>(q_l, q_r, v_l, v_r, f_r2l, f_l2r);

    p3m_k<<<g_p3, blk, 0, stream>>>(f_r2l, f_l2r, wf16 + 4 * 4096, lp3_b, wf16 + 5 * 4096, rp3_b, clA0);

    p4m_k<<<g_p4, blk, 0, stream>>>(x_l, x_r, clA0, tbl, pa_b, (float*)d_out);
}

// Round 13
// 286.502 us; speedup vs baseline: 1.0367x; 1.0367x over previous
//
#include <hip/hip_runtime.h>

typedef unsigned int uint;
typedef unsigned short ushort;
typedef _Float16 h2 __attribute__((ext_vector_type(2)));
typedef _Float16 f16x8 __attribute__((ext_vector_type(8)));
typedef float f32x4 __attribute__((ext_vector_type(4)));

#define HW 65536
#define W_ 256
#define H_ 256
#define C_ 64

__device__ __forceinline__ ushort f2hu(float f) { union { ushort u; _Float16 h; } x; x.h = (_Float16)f; return x.u; }
__device__ __forceinline__ float hu2f(ushort u) { union { ushort u; _Float16 h; } x; x.u = u; return (float)x.h; }

#define MFMA16(a, b, c) __builtin_amdgcn_mfma_f32_16x16x32_f16((a), (b), (c), 0, 0, 0)

// ---------------- convert 6 weight matrices (4096 fp32 each) to f16, same [o][c] layout ----------------
__global__ __launch_bounds__(256) void wconv_k(const float* __restrict__ a0, const float* __restrict__ a1,
                                               const float* __restrict__ a2, const float* __restrict__ a3,
                                               const float* __restrict__ a4, const float* __restrict__ a5,
                                               ushort* __restrict__ dst) {
    int m = blockIdx.x;
    const float* src = m == 0 ? a0 : m == 1 ? a1 : m == 2 ? a2 : m == 3 ? a3 : m == 4 ? a4 : a5;
    ushort* d = dst + m * 4096;
    for (int i = threadIdx.x; i < 4096; i += 256) d[i] = f2hu(src[i]);
}

// ---------------- build Toeplitz B-fragments for the 7x7 pixel-attention conv ----------------
__global__ __launch_bounds__(256) void wpat_k(const float* __restrict__ pw, ushort* __restrict__ tbl) {
    int c = blockIdx.x;
    for (int i = threadIdx.x; i < 7168; i += 256) {
        int j = i & 7;
        int lane = (i >> 3) & 63;
        int f = i >> 9;              // 0..13
        int arr = f < 7 ? 0 : 1;
        int dy = f < 7 ? f : f - 7;
        int l15 = lane & 15, quad = lane >> 4;
        int k = quad * 8 + j;
        int t = k - l15 - 1;
        float v = (t >= 0 && t < 7) ? pw[c * 98 + arr * 49 + dy * 7 + t] : 0.0f;
        tbl[c * 7168 + i] = f2hu(v);
    }
}

// ---------------- fused dual conv1x1, 128-pixel tiles, fully-coalesced channels-last store ----------------
// sS [c][pix] stride 132 for staging+frags; sP [pix][ch] stride 80 for epilogue; store = contiguous 16KB.
__global__ __launch_bounds__(256, 4) void c1df_k(const float* __restrict__ xl,
                                                 const float* __restrict__ xr,
                                                 const ushort* __restrict__ wf16,
                                                 const float* __restrict__ bA0, const float* __restrict__ bB0,
                                                 const float* __restrict__ bA1, const float* __restrict__ bB1,
                                                 ushort* __restrict__ y0A, ushort* __restrict__ y0B,
                                                 ushort* __restrict__ y1A, ushort* __restrict__ y1B) {
    __shared__ ushort sS[64 * 132];     // staging [c][pix]
    __shared__ ushort sP[128 * 80];     // epilogue [pix][ch], stride 80
    int side = blockIdx.y;
    const float* x = side ? xr : xl;
    const ushort* wfA = wf16 + side * 4096;
    const ushort* wfB = wf16 + (2 + side) * 4096;
    const float* biasA = side ? bA1 : bA0;
    const float* biasB = side ? bB1 : bB0;
    ushort* yAo = side ? y1A : y0A;
    ushort* yBo = side ? y1B : y0B;

    int tid = threadIdx.x;
    int wv = tid >> 6, lane = tid & 63;
    int l15 = lane & 15, quad = lane >> 4;
    int pix0 = blockIdx.x * 128;
    int b = pix0 >> 16, hw0 = pix0 & 65535;
    const float* xb = x + ((size_t)b << 22) + hw0;

    // ---- stage: 8 x float4 coalesced loads -> f16 LDS [c][pix] ----
#pragma unroll
    for (int i = 0; i < 8; ++i) {
        int idx = i * 256 + tid;        // 0..2047
        int cc = idx >> 5;              // channel 0..63
        int p4 = idx & 31;              // float4 index -> pixels p4*4..p4*4+3
        float4 v = *(const float4*)(xb + ((size_t)cc << 16) + p4 * 4);
        uint2 pk;
        pk.x = (uint)f2hu(v.x) | ((uint)f2hu(v.y) << 16);
        pk.y = (uint)f2hu(v.z) | ((uint)f2hu(v.w) << 16);
        *(uint2*)&sS[cc * 132 + p4 * 4] = pk;
    }
    __syncthreads();                    // B1: staging visible

    // ---- A-frags from LDS: pixel = wv*32+mt*16+l15, channel = kc*32+quad*8+j ----
    f16x8 aX[2][2];
#pragma unroll
    for (int mt = 0; mt < 2; ++mt) {
        int pixl = wv * 32 + mt * 16 + l15;
#pragma unroll
        for (int kc = 0; kc < 2; ++kc) {
            f16x8 a;
#pragma unroll
            for (int j = 0; j < 8; ++j) {
                int c = kc * 32 + quad * 8 + j;
                a[j] = *(const _Float16*)&sS[c * 132 + pixl];
            }
            aX[mt][kc] = a;
        }
    }

    for (int mat = 0; mat < 2; ++mat) {
        const ushort* wf = mat == 0 ? wfA : wfB;
        const float* bias = mat == 0 ? biasA : biasB;
        ushort* y = mat == 0 ? yAo : yBo;

        f16x8 bW[4][2];
#pragma unroll
        for (int nt = 0; nt < 4; ++nt)
#pragma unroll
            for (int kc = 0; kc < 2; ++kc)
                bW[nt][kc] = *(const f16x8*)(wf + (nt * 16 + l15) * 64 + kc * 32 + quad * 8);

        f32x4 acc[2][4];
#pragma unroll
        for (int mt = 0; mt < 2; ++mt)
#pragma unroll
            for (int nt = 0; nt < 4; ++nt) {
                f32x4 s = (f32x4)(0.0f);
                s = MFMA16(aX[mt][0], bW[nt][0], s);
                s = MFMA16(aX[mt][1], bW[nt][1], s);
                acc[mt][nt] = s;
            }

        if (mat == 1) __syncthreads();  // mat0's sP store-reads done before overwrite
        // ---- epilogue -> sP [pix][ch] (scalar u16, 2-way banks) ----
#pragma unroll
        for (int nt = 0; nt < 4; ++nt) {
            int o = nt * 16 + l15;
            float bv = bias[o];
#pragma unroll
            for (int mt = 0; mt < 2; ++mt) {
                int pixl = wv * 32 + mt * 16 + quad * 4;
#pragma unroll
                for (int r = 0; r < 4; ++r)
                    sP[(pixl + r) * 80 + o] = f2hu(acc[mt][nt][r] + bv);
            }
        }
        __syncthreads();                // epilogue visible
        // ---- fully-coalesced store: tile output = contiguous 16KB; lane-consecutive uint4 ----
        ushort* ybase = y + (((size_t)b << 16) + hw0) * 64;
#pragma unroll
        for (int q = 0; q < 4; ++q) {
            int u = q * 256 + tid;      // 0..1023 uint4 index
            int px = u >> 3, ch0 = (u & 7) * 8;
            uint4 o = *(const uint4*)&sP[px * 80 + ch0];
            *(uint4*)(ybase + (size_t)u * 8) = o;
        }
    }
}

// ------- merged depthwise 3x3: Q path (mode 0, channels-last out) + V path (mode 1, plane out) -------
__global__ __launch_bounds__(256) void dwqv_k(const ushort* __restrict__ xA0, const ushort* __restrict__ xA1,
                                              const ushort* __restrict__ xB0, const ushort* __restrict__ xB1,
                                              const float* __restrict__ wq0, const float* __restrict__ wq1,
                                              const float* __restrict__ wv0, const float* __restrict__ wv1,
                                              const float* __restrict__ bq0, const float* __restrict__ bq1,
                                              const float* __restrict__ bv0, const float* __restrict__ bv1,
                                              ushort* __restrict__ oq0, ushort* __restrict__ oq1,
                                              ushort* __restrict__ ov0, ushort* __restrict__ ov1) {
    int z = blockIdx.z;
    int mode = z >> 2, side = (z >> 1) & 1, b = z & 1;
    const ushort* xcl = mode ? (side ? xB1 : xB0) : (side ? xA1 : xA0);
    const float* wgt  = mode ? (side ? wv1 : wv0) : (side ? wq1 : wq0);
    const float* bias = mode ? (side ? bv1 : bv0) : (side ? bq1 : bq0);
    ushort* out       = mode ? (side ? ov1 : ov0) : (side ? oq1 : oq0);

    __shared__ float sW[576];
    __shared__ ushort sT[4][64 * 66];
    int tid = threadIdx.x;
    for (int i = tid; i < 576; i += 256) sW[i] = wgt[i];
    __syncthreads();
    int c = tid & 63, wq = tid >> 6;
    int wt = blockIdx.x, h0 = blockIdx.y * 4;
    int wbase = wt * 64 + wq * 16;
    const float* wp = sW + c * 9;
    float bv = bias[c];
    float acc[4][16];
#pragma unroll
    for (int o = 0; o < 4; ++o)
#pragma unroll
        for (int i = 0; i < 16; ++i) acc[o][i] = bv;
    size_t plane = (size_t)b << 16;
#pragma unroll
    for (int r = 0; r < 6; ++r) {
        int hh = h0 - 1 + r;
        int hhc = hh < 0 ? 0 : (hh > 255 ? 255 : hh);
        bool okh = (hh >= 0 && hh <= 255);
        float v[18];
#pragma unroll
        for (int t = 0; t < 18; ++t) {
            int ww = wbase - 1 + t;
            int wwc = ww < 0 ? 0 : (ww > 255 ? 255 : ww);
            float xv = hu2f(xcl[((plane + (size_t)hhc * 256 + wwc) << 6) + c]);
            v[t] = (okh && ww >= 0 && ww <= 255) ? xv : 0.0f;
        }
#pragma unroll
        for (int o = 0; o < 4; ++o) {
            if (o >= r - 2 && o <= r) {          // weight row wr = r - o in 0..2
                int wr = r - o;
                float wa = wp[wr * 3], wb = wp[wr * 3 + 1], wc2 = wp[wr * 3 + 2];
#pragma unroll
                for (int i = 0; i < 16; ++i)
                    acc[o][i] += wa * v[i] + wb * v[i + 1] + wc2 * v[i + 2];
            }
        }
    }

    if (mode == 0) {
        // Q path: channels-last store, lane = c coalesced
#pragma unroll
        for (int o = 0; o < 4; ++o) {
            size_t obase = ((plane + (size_t)(h0 + o) * 256 + wbase) << 6) + c;
#pragma unroll
            for (int i = 0; i < 16; ++i)
                out[obase + ((size_t)i << 6)] = f2hu(acc[o][i]);
        }
    } else {
        // V path: transpose through LDS to plane layout [bh][c][w]
#pragma unroll
        for (int o = 0; o < 4; ++o)
#pragma unroll
            for (int i = 0; i < 16; i += 2) {
                h2 hh2;
                hh2.x = (_Float16)acc[o][i];
                hh2.y = (_Float16)acc[o][i + 1];
                *(h2*)&sT[o][c * 66 + wq * 16 + i] = hh2;
            }
        __syncthreads();
        int cr = tid >> 2, ch = tid & 3;
#pragma unroll
        for (int o = 0; o < 4; ++o) {
            uint vb[8];
#pragma unroll
            for (int k = 0; k < 8; ++k) vb[k] = *(const uint*)&sT[o][cr * 66 + ch * 16 + k * 2];
            uint4 q0, q1;
            q0.x = vb[0]; q0.y = vb[1]; q0.z = vb[2]; q0.w = vb[3];
            q1.x = vb[4]; q1.y = vb[5]; q1.z = vb[6]; q1.w = vb[7];
            size_t bh16 = ((size_t)b * 256 + h0 + o) * 16384;
            ushort* ob = out + bh16 + (size_t)cr * 256 + wt * 64 + ch * 16;
            *(uint4*)ob = q0;
            *(uint4*)(ob + 8) = q1;
        }
    }
}

// ---------------- combined MFMA attention (verified 256-thread version, 40us) ----------------
__global__ __launch_bounds__(256, 2) void att2_k(const ushort* __restrict__ Ql,
                                                 const ushort* __restrict__ Qr,
                                                 const ushort* __restrict__ Vl,
                                                 const ushort* __restrict__ Vr,
                                                 ushort* __restrict__ Fr2l,
                                                 ushort* __restrict__ Fl2r) {
    int bh = blockIdx.x;
    int tid = threadIdx.x;
    int wv = tid >> 6, lane = tid & 63;
    int l15 = lane & 15, quad = lane >> 4;
    __shared__ ushort sE[256 * 72];    // E row-major [p][kcol], stride 72
    __shared__ ushort sEt[64 * 264];   // E col-major [kcol][p], stride 264

    const ushort* qlb = Ql + (size_t)bh * 16384;
    const ushort* qrb = Qr + (size_t)bh * 16384;
    const ushort* vlb = Vl + (size_t)bh * 16384;
    const ushort* vrb = Vr + (size_t)bh * 16384;
    int p0 = wv * 64;
    int c0 = wv * 16;

    f16x8 aQ[4][2];
#pragma unroll
    for (int mt = 0; mt < 4; ++mt)
#pragma unroll
        for (int kc = 0; kc < 2; ++kc)
            aQ[mt][kc] = *(const f16x8*)(qlb + (p0 + mt * 16 + l15) * 64 + kc * 32 + quad * 8);

    f16x8 onesf;
#pragma unroll
    for (int i = 0; i < 8; ++i) onesf[i] = (_Float16)1.0f;

    f32x4 num1[4][4];
    f32x4 den[4];
#pragma unroll
    for (int mt = 0; mt < 4; ++mt) {
        den[mt] = (f32x4)(0.0f);
#pragma unroll
        for (int nt = 0; nt < 4; ++nt) num1[mt][nt] = (f32x4)(0.0f);
    }

    for (int kt = 0; kt < 4; ++kt) {
        int k0 = kt * 64;
        f32x4 S[4][4];
#pragma unroll
        for (int nt = 0; nt < 4; ++nt) {
            f16x8 bQ[2];
#pragma unroll
            for (int kc = 0; kc < 2; ++kc)
                bQ[kc] = *(const f16x8*)(qrb + (k0 + nt * 16 + l15) * 64 + kc * 32 + quad * 8);
#pragma unroll
            for (int mt = 0; mt < 4; ++mt) {
                f32x4 s = (f32x4)(0.0f);
                s = MFMA16(aQ[mt][0], bQ[0], s);
                s = MFMA16(aQ[mt][1], bQ[1], s);
                S[mt][nt] = s;
            }
        }
#pragma unroll
        for (int mt = 0; mt < 4; ++mt)
#pragma unroll
            for (int nt = 0; nt < 4; ++nt)
#pragma unroll
                for (int r = 0; r < 4; ++r)
                    S[mt][nt][r] = __expf(S[mt][nt][r] * 0.125f);

        __syncthreads();
#pragma unroll
        for (int mt = 0; mt < 4; ++mt)
#pragma unroll
            for (int nt = 0; nt < 4; ++nt)
#pragma unroll
                for (int r = 0; r < 4; ++r)
                    sE[(p0 + mt * 16 + quad * 4 + r) * 72 + nt * 16 + l15] = f2hu(S[mt][nt][r]);
#pragma unroll
        for (int mt = 0; mt < 4; ++mt)
#pragma unroll
            for (int nt = 0; nt < 4; ++nt)
#pragma unroll
            for (int pr = 0; pr < 4; pr += 2) {
                h2 hh;
                hh.x = (_Float16)S[mt][nt][pr];
                hh.y = (_Float16)S[mt][nt][pr + 1];
                *(h2*)&sEt[(nt * 16 + l15) * 264 + p0 + mt * 16 + quad * 4 + pr] = hh;
            }
        __syncthreads();

        f16x8 aE[4][2];
#pragma unroll
        for (int mt = 0; mt < 4; ++mt)
#pragma unroll
            for (int kc = 0; kc < 2; ++kc)
                aE[mt][kc] = *(const f16x8*)&sE[(p0 + mt * 16 + l15) * 72 + kc * 32 + quad * 8];
#pragma unroll
        for (int mt = 0; mt < 4; ++mt) {
            den[mt] = MFMA16(aE[mt][0], onesf, den[mt]);
            den[mt] = MFMA16(aE[mt][1], onesf, den[mt]);
        }
#pragma unroll
        for (int nt = 0; nt < 4; ++nt) {
            f16x8 bV[2];
#pragma unroll
            for (int kc = 0; kc < 2; ++kc)
                bV[kc] = *(const f16x8*)(vrb + (nt * 16 + l15) * 256 + k0 + kc * 32 + quad * 8);
#pragma unroll
            for (int mt = 0; mt < 4; ++mt) {
                num1[mt][nt] = MFMA16(aE[mt][0], bV[0], num1[mt][nt]);
                num1[mt][nt] = MFMA16(aE[mt][1], bV[1], num1[mt][nt]);
            }
        }
        f32x4 num2[4], den2[4];
#pragma unroll
        for (int mt = 0; mt < 4; ++mt) { num2[mt] = (f32x4)(0.0f); den2[mt] = (f32x4)(0.0f); }
        for (int pc = 0; pc < 8; ++pc) {
            f16x8 bL = *(const f16x8*)(vlb + (c0 + l15) * 256 + pc * 32 + quad * 8);
#pragma unroll
            for (int mt = 0; mt < 4; ++mt) {
                f16x8 aT = *(const f16x8*)&sEt[(mt * 16 + l15) * 264 + pc * 32 + quad * 8];
                num2[mt] = MFMA16(aT, bL, num2[mt]);
                den2[mt] = MFMA16(aT, onesf, den2[mt]);
            }
        }
#pragma unroll
        for (int mt = 0; mt < 4; ++mt)
#pragma unroll
            for (int r = 0; r < 4; ++r) {
                float v = num2[mt][r] * (1.0f / den2[mt][r]);
                Fl2r[(size_t)bh * 16384 + (k0 + mt * 16 + quad * 4 + r) * 64 + c0 + l15] = f2hu(v);
            }
    }
#pragma unroll
    for (int mt = 0; mt < 4; ++mt)
#pragma unroll
        for (int r = 0; r < 4; ++r) {
            float inv = 1.0f / den[mt][r];
#pragma unroll
            for (int nt = 0; nt < 4; ++nt) {
                float v = num1[mt][nt][r] * inv;
                Fr2l[(size_t)bh * 16384 + (p0 + mt * 16 + quad * 4 + r) * 64 + nt * 16 + l15] = f2hu(v);
            }
        }
}

// ------- pattn1 = lp3(F_r2l) + rp3(F_l2r) via MFMA; channels-last f16 in, NCHW f16 out -------
__global__ __launch_bounds__(256, 2) void p3m_k(const ushort* __restrict__ F1,
                                                const ushort* __restrict__ F2,
                                                const ushort* __restrict__ wf1,
                                                const float* __restrict__ b1,
                                                const ushort* __restrict__ wf2,
                                                const float* __restrict__ b2,
                                                ushort* __restrict__ outp) {
    __shared__ ushort sY[64 * 264];
    int tid = threadIdx.x;
    int wv = tid >> 6, lane = tid & 63;
    int l15 = lane & 15, quad = lane >> 4;
    int pix0 = blockIdx.x * 256;
    int b = pix0 >> 16, hw0 = pix0 & 65535;

    f32x4 acc[4][4];
#pragma unroll
    for (int mt = 0; mt < 4; ++mt)
#pragma unroll
        for (int nt = 0; nt < 4; ++nt) acc[mt][nt] = (f32x4)(0.0f);

    for (int mat = 0; mat < 2; ++mat) {
        const ushort* F = mat == 0 ? F1 : F2;
        const ushort* wf = mat == 0 ? wf1 : wf2;
        f16x8 aF[4][2], bW[4][2];
#pragma unroll
        for (int mt = 0; mt < 4; ++mt) {
            int pixg = pix0 + wv * 64 + mt * 16 + l15;
#pragma unroll
            for (int kc = 0; kc < 2; ++kc)
                aF[mt][kc] = *(const f16x8*)(F + (size_t)pixg * 64 + kc * 32 + quad * 8);
        }
#pragma unroll
        for (int nt = 0; nt < 4; ++nt)
#pragma unroll
            for (int kc = 0; kc < 2; ++kc)
                bW[nt][kc] = *(const f16x8*)(wf + (nt * 16 + l15) * 64 + kc * 32 + quad * 8);
#pragma unroll
        for (int mt = 0; mt < 4; ++mt)
#pragma unroll
            for (int nt = 0; nt < 4; ++nt) {
                acc[mt][nt] = MFMA16(aF[mt][0], bW[nt][0], acc[mt][nt]);
                acc[mt][nt] = MFMA16(aF[mt][1], bW[nt][1], acc[mt][nt]);
            }
    }

#pragma unroll
    for (int nt = 0; nt < 4; ++nt) {
        int o = nt * 16 + l15;
        float bv = b1[o] + b2[o];
#pragma unroll
        for (int mt = 0; mt < 4; ++mt) {
            int pixl = wv * 64 + mt * 16 + quad * 4;
#pragma unroll
            for (int r = 0; r < 4; r += 2) {
                h2 hh;
                hh.x = (_Float16)(acc[mt][nt][r] + bv);
                hh.y = (_Float16)(acc[mt][nt][r + 1] + bv);
                *(h2*)&sY[o * 264 + pixl + r] = hh;
            }
        }
    }
    __syncthreads();
    ushort* yb = outp + ((size_t)b << 22) + hw0;
#pragma unroll
    for (int i = 0; i < 16; ++i) {
        int o = wv * 16 + i;
        uint2 v = *(const uint2*)&sY[o * 264 + lane * 4];
        *(uint2*)(yb + ((size_t)o << 16) + lane * 4) = v;
    }
}

// ------- pixel attention 7x7 reflect + double sigmoid + blend, via Toeplitz MFMA -------
__global__ __launch_bounds__(256, 4) void p4m_k(const float* __restrict__ x_l,
                                                const float* __restrict__ x_r,
                                                const ushort* __restrict__ pt,
                                                const ushort* __restrict__ tbl,
                                                const float* __restrict__ pb,
                                                float* __restrict__ out) {
    __shared__ ushort s_t[22 * 320];
    __shared__ ushort p_t[22 * 320];
    int tid = threadIdx.x;
    int tile = blockIdx.x & 15;
    int bc = blockIdx.x >> 4;        // b*64 + c
    int c = bc & 63;
    int h0 = tile << 4;
    size_t cbase = (size_t)bc << 16;

    {
        int a = tid & 127, rr = tid >> 7;
        int k = 2 * a + 4;
        int slotbase = (k >> 3);
        for (int pass = 0; pass < 11; ++pass) {
            int row = pass * 2 + rr;
            int hh = h0 + row - 3;
            hh = hh < 0 ? -hh : (hh > 255 ? 510 - hh : hh);
            size_t rb = cbase + ((size_t)hh << 8);
            float2 xl2 = *(const float2*)(x_l + rb + 2 * a);
            float2 xr2 = *(const float2*)(x_r + rb + 2 * a);
            uint pv = *(const uint*)(pt + rb + 2 * a);
            h2 sh;
            sh.x = (_Float16)(xl2.x + xr2.x);
            sh.y = (_Float16)(xl2.y + xr2.y);
            int off = row * 320 + (((slotbase ^ (row & 7)) << 3) | (k & 7));
            *(h2*)&s_t[off] = sh;
            *(uint*)&p_t[off] = pv;
        }
    }
    if (tid < 176) {
        int row = tid >> 3, g = tid & 7;
        int k = g < 2 ? g * 2 : (g < 4 ? 260 + (g - 2) * 2 : 264 + (g - 4) * 2);
        h2 sh; uint pv;
        if (g < 4) {
            int hh = h0 + row - 3;
            hh = hh < 0 ? -hh : (hh > 255 ? 510 - hh : hh);
            size_t rb = cbase + ((size_t)hh << 8);
            int w0 = k - 4, w1 = k - 3;
            int s0 = w0 < 0 ? -w0 : (w0 > 255 ? 510 - w0 : w0);
            int s1 = w1 < 0 ? -w1 : (w1 > 255 ? 510 - w1 : w1);
            sh.x = (_Float16)(x_l[rb + s0] + x_r[rb + s0]);
            sh.y = (_Float16)(x_l[rb + s1] + x_r[rb + s1]);
            pv = (uint)pt[rb + s0] | ((uint)pt[rb + s1] << 16);
        } else {
            sh.x = (_Float16)0.0f; sh.y = (_Float16)0.0f;
            pv = 0;
        }
        int off = row * 320 + ((((k >> 3) ^ (row & 7)) << 3) | (k & 7));
        *(h2*)&s_t[off] = sh;
        *(uint*)&p_t[off] = pv;
    }

    int wv = tid >> 6, lane = tid & 63;
    int l15 = lane & 15, quad = lane >> 4;
    const ushort* tb = tbl + c * 7168;
    f16x8 bW[14];
#pragma unroll
    for (int f = 0; f < 14; ++f)
        bW[f] = *(const f16x8*)(tb + (f * 64 + lane) * 8);

    float bias = pb[c];
    f32x4 acc[4];
#pragma unroll
    for (int t = 0; t < 4; ++t) acc[t] = (f32x4)(bias);

    __syncthreads();

#pragma unroll
    for (int f = 0; f < 14; ++f) {
        int dy = f < 7 ? f : f - 7;
        const ushort* tp = f < 7 ? s_t : p_t;
        int row = l15 + dy;
        int rbase = row * 320;
        int rx = row & 7;
#pragma unroll
        for (int t = 0; t < 4; ++t) {
            int L = wv * 8 + 2 * t + quad;
            f16x8 aF = *(const f16x8*)&tp[rbase + ((L ^ rx) << 3)];
            acc[t] = MFMA16(aF, bW[f], acc[t]);
        }
    }

    int hrow = h0 + quad * 4;
#pragma unroll
    for (int t = 0; t < 4; ++t) {
        int w = wv * 64 + t * 16 + l15;
#pragma unroll
        for (int r = 0; r < 4; ++r) {
            size_t idx = cbase + (size_t)(hrow + r) * 256 + w;
            float z = acc[t][r];
            float s1 = 1.0f / (1.0f + __expf(-z));
            float a  = 1.0f / (1.0f + __expf(-s1));
            float xl = x_l[idx], xr = x_r[idx];
            out[idx] = xr + a * (xl - xr);
        }
    }
}

extern "C" void kernel_launch(void* const* d_in, const int* in_sizes, int n_in,
                              void* d_out, int out_size, void* d_ws, size_t ws_size,
                              hipStream_t stream) {
    const float* x_l = (const float*)d_in[0];
    const float* x_r = (const float*)d_in[1];
    const float* lp1_w1 = (const float*)d_in[2];
    const float* lp1_b1 = (const float*)d_in[3];
    const float* lp1_w2 = (const float*)d_in[4];
    const float* lp1_b2 = (const float*)d_in[5];
    const float* rp1_w1 = (const float*)d_in[6];
    const float* rp1_b1 = (const float*)d_in[7];
    const float* rp1_w2 = (const float*)d_in[8];
    const float* rp1_b2 = (const float*)d_in[9];
    const float* lp2_w1 = (const float*)d_in[10];
    const float* lp2_b1 = (const float*)d_in[11];
    const float* lp2_w2 = (const float*)d_in[12];
    const float* lp2_b2 = (const float*)d_in[13];
    const float* rp2_w1 = (const float*)d_in[14];
    const float* rp2_b1 = (const float*)d_in[15];
    const float* rp2_w2 = (const float*)d_in[16];
    const float* rp2_b2 = (const float*)d_in[17];
    const float* lp3_w = (const float*)d_in[18];
    const float* lp3_b = (const float*)d_in[19];
    const float* rp3_w = (const float*)d_in[20];
    const float* rp3_b = (const float*)d_in[21];
    const float* pa_w = (const float*)d_in[22];
    const float* pa_b = (const float*)d_in[23];

    const size_t N = (size_t)2 * 64 * 256 * 256;    // 8388608
    char* ws = (char*)d_ws;
    ushort* clA0 = (ushort*)ws;                     // N u16 (side0 Q-path c1 out / later pattn1 NCHW)
    ushort* wf16 = (ushort*)(ws + N * 2);           // 6 * 4096 f16 weights [o][c]
    ushort* tbl  = (ushort*)(ws + N * 2 + 6 * 4096 * 2);  // Toeplitz frags (~0.9MB)
    ushort* q_l   = (ushort*)(ws + N * 4);
    ushort* q_r   = q_l + N;
    ushort* v_l   = q_r + N;                        // plane layout
    ushort* v_r   = v_l + N;                        // plane layout
    ushort* f_r2l = v_r + N;
    ushort* f_l2r = f_r2l + N;
    ushort* clB0  = f_l2r + N;                      // side0 V-path c1 out
    ushort* clA1  = clB0 + N;                       // side1 Q-path
    ushort* clB1  = clA1 + N;                       // side1 V-path

    dim3 blk(256);
    dim3 g_c1(1024, 2);        // B*HW/128, side
    dim3 g_dw(4, 64, 8);       // wtile, hquad, mode*4+side*2+b
    dim3 g_att(512);           // b*h
    dim3 g_p3(512);            // B*HW/256
    dim3 g_p4(2048);           // (b*64+c)*16 + htile

    wconv_k<<<6, blk, 0, stream>>>(lp1_w1, rp1_w1, lp2_w1, rp2_w1, lp3_w, rp3_w, wf16);
    wpat_k<<<64, blk, 0, stream>>>(pa_w, tbl);

    c1df_k<<<g_c1, blk, 0, stream>>>(x_l, x_r, wf16,
                                     lp1_b1, lp2_b1, rp1_b1, rp2_b1,
                                     clA0, clB0, clA1, clB1);
    dwqv_k<<<g_dw, blk, 0, stream>>>(clA0, clA1, clB0, clB1,
                                     lp1_w2, rp1_w2, lp2_w2, rp2_w2,
                                     lp1_b2, rp1_b2, lp2_b2, rp2_b2,
                                     q_l, q_r, v_l, v_r);

    att2_k<<<g_att, blk, 0, stream>>>(q_l, q_r, v_l, v_r, f_r2l, f_l2r);

    p3m_k<<<g_p3, blk, 0, stream>>>(f_r2l, f_l2r, wf16 + 4 * 4096, lp3_b, wf16 + 5 * 4096, rp3_b, clA0);

    p4m_k<<<g_p4, blk, 0, stream>>>(x_l, x_r, clA0, tbl, pa_b, (float*)d_out);
}